// Round 4
// baseline (353.872 us; speedup 1.0000x reference)
//
#include <hip/hip_runtime.h>

#define N_ENT 500000
#define N_REL 200
#define DIMS 128
#define BATCH 16384
#define MARGIN 1.0f
#define CHUNK 16
#define GRID_MAIN 1280
#define TBL_BASE 16        // chunk table base (int idx), 1280 entries
#define ACC_BASE 8192      // 128 float accumulator slots (int idx)
#define EIDX_BASE 65536    // per-relation pregathered entity-id regions
#define REGION_STRIDE 65536  // ints per relation region (16384 rows x 4 ids)

// ---------------- bucketing: one WG per relation ---------------------------
// WG r scans data[:,2], pre-gathers (h,t,ch,ct) entity ids for its rows into
// region r, then reserves chunk-table slots with ONE global atomic.
__global__ void __launch_bounds__(256) k_bucket(const int* __restrict__ data,
                                                int* __restrict__ wsi) {
    __shared__ int lcnt, lbase;
    const int r   = blockIdx.x;
    const int tid = threadIdx.x;
    if (tid == 0) lcnt = 0;
    __syncthreads();

    int* region = wsi + EIDX_BASE + r * REGION_STRIDE;
    for (int i = tid; i < BATCH; i += 256) {
        const int* row = data + i * 5;
        if (row[2] == r) {
            int p = atomicAdd(&lcnt, 1);
            int4 e;
            e.x = row[0]; e.y = row[1]; e.z = row[3]; e.w = row[4];
            *reinterpret_cast<int4*>(region + p * 4) = e;
        }
    }
    __syncthreads();

    const int total = lcnt;
    const int nch   = (total + 15) >> 4;
    if (tid == 0 && nch > 0) lbase = atomicAdd(&wsi[0], nch);
    __syncthreads();
    for (int k = tid; k < nch; k += 256) {
        int take = min(16, total - k * 16);
        // entry: r in bits 16+, chunk idx k in bits 5..15, cnt in bits 0..4
        wsi[TBL_BASE + lbase + k] = (r << 16) | (k << 5) | take;
    }
}

__device__ __forceinline__ void fma4(float4& a, float s, const float4& b) {
    a.x = fmaf(s, b.x, a.x);
    a.y = fmaf(s, b.y, a.y);
    a.z = fmaf(s, b.z, a.z);
    a.w = fmaf(s, b.w, a.w);
}
__device__ __forceinline__ float dot4(const float4& x, const float4& y) {
    return x.x * y.x + x.y * y.y + x.z * y.z + x.w * y.w;
}

// ---------------- main: one chunk (<=16 rows, one relation) per WG ---------
// Lane (a,b): a=tid>>4 owns R rows 8a..8a+7, b=tid&15 owns cols 8b..8b+7.
__global__ void __launch_bounds__(256) k_main(const float* __restrict__ ent,
                                              const float* __restrict__ rel,
                                              int* __restrict__ wsi) {
    __shared__ float4 sh[16][4][32];  // row g, kind (h,t,ch,ct), float4 idx
    __shared__ float parts[4][16];    // wave x row

    const int tid  = threadIdx.x;
    const int a    = tid >> 4;
    const int b    = tid & 15;
    const int wave = tid >> 6;
    const int lane = tid & 63;

    const int entry = wsi[TBL_BASE + blockIdx.x];
    if (entry == 0) return;  // uniform exit, before barriers

    const int r   = entry >> 16;
    const int k16 = (entry >> 5) & 0x7FF;
    const int cnt = entry & 31;

    // Register-resident R tile: rows 8a+k, cols 8b..8b+7
    const float* Rg = rel + (size_t)r * (DIMS * DIMS);
    float4 Rr[16];
#pragma unroll
    for (int k = 0; k < 8; ++k) {
        const float* rp = Rg + (size_t)(8 * a + k) * DIMS + 8 * b;
        Rr[2 * k]     = *reinterpret_cast<const float4*>(rp);
        Rr[2 * k + 1] = *reinterpret_cast<const float4*>(rp + 4);
    }

    // Stage entities: pregathered ids, 2048 float4 loads total
    const int* eidx = wsi + EIDX_BASE + r * REGION_STRIDE + k16 * 64;
#pragma unroll
    for (int it = 0; it < 8; ++it) {
        int idx  = tid + it * 256;
        int f4   = idx & 31;
        int vid  = idx >> 5;
        int kind = vid & 3;
        int g    = vid >> 2;
        int gg   = (g < cnt) ? g : (cnt - 1);   // clamp BEFORE id load
        int e    = eidx[gg * 4 + kind];
        sh[g][kind][f4] =
            *reinterpret_cast<const float4*>(ent + (size_t)e * DIMS + f4 * 4);
    }
    __syncthreads();

    for (int g = 0; g < 16; ++g) {
        const float4* hp = &sh[g][0][0];
        const float4* tp = &sh[g][1][0];
        const float4* cp = &sh[g][2][0];
        const float4* dp = &sh[g][3][0];
        float4 h0 = hp[2 * a], h1 = hp[2 * a + 1];
        float4 c0 = cp[2 * a], c1 = cp[2 * a + 1];
        float4 up0 = {0.f, 0.f, 0.f, 0.f}, up1 = up0, un0 = up0, un1 = up0;
        fma4(up0, h0.x, Rr[0]);  fma4(up1, h0.x, Rr[1]);
        fma4(up0, h0.y, Rr[2]);  fma4(up1, h0.y, Rr[3]);
        fma4(up0, h0.z, Rr[4]);  fma4(up1, h0.z, Rr[5]);
        fma4(up0, h0.w, Rr[6]);  fma4(up1, h0.w, Rr[7]);
        fma4(up0, h1.x, Rr[8]);  fma4(up1, h1.x, Rr[9]);
        fma4(up0, h1.y, Rr[10]); fma4(up1, h1.y, Rr[11]);
        fma4(up0, h1.z, Rr[12]); fma4(up1, h1.z, Rr[13]);
        fma4(up0, h1.w, Rr[14]); fma4(up1, h1.w, Rr[15]);
        fma4(un0, c0.x, Rr[0]);  fma4(un1, c0.x, Rr[1]);
        fma4(un0, c0.y, Rr[2]);  fma4(un1, c0.y, Rr[3]);
        fma4(un0, c0.z, Rr[4]);  fma4(un1, c0.z, Rr[5]);
        fma4(un0, c0.w, Rr[6]);  fma4(un1, c0.w, Rr[7]);
        fma4(un0, c1.x, Rr[8]);  fma4(un1, c1.x, Rr[9]);
        fma4(un0, c1.y, Rr[10]); fma4(un1, c1.y, Rr[11]);
        fma4(un0, c1.z, Rr[12]); fma4(un1, c1.z, Rr[13]);
        fma4(un0, c1.w, Rr[14]); fma4(un1, c1.w, Rr[15]);
        float4 t0 = tp[2 * b], t1 = tp[2 * b + 1];
        float4 d0 = dp[2 * b], d1 = dp[2 * b + 1];
        float s = dot4(up0, t0) + dot4(up1, t1) - dot4(un0, d0) - dot4(un1, d1);
        s += __shfl_xor(s, 32, 64);
        s += __shfl_xor(s, 16, 64);
        s += __shfl_xor(s, 8, 64);
        s += __shfl_xor(s, 4, 64);
        s += __shfl_xor(s, 2, 64);
        s += __shfl_xor(s, 1, 64);
        if (lane == 0) parts[wave][g] = s;
    }
    __syncthreads();

    if (tid < 16) {
        float v = parts[0][tid] + parts[1][tid] + parts[2][tid] + parts[3][tid]
                + MARGIN;
        v = (tid < cnt && v > 0.0f) ? v : 0.0f;
        v += __shfl_xor(v, 8, 64);
        v += __shfl_xor(v, 4, 64);
        v += __shfl_xor(v, 2, 64);
        v += __shfl_xor(v, 1, 64);
        if (tid == 0)
            atomicAdd(reinterpret_cast<float*>(wsi) + ACC_BASE + (blockIdx.x & 127), v);
    }
}

__global__ void k_final(const int* __restrict__ wsi, float* __restrict__ out) {
    const float* acc = reinterpret_cast<const float*>(wsi) + ACC_BASE;
    int t = threadIdx.x;
    float v = acc[t] + acc[t + 64];
    v += __shfl_xor(v, 32, 64);
    v += __shfl_xor(v, 16, 64);
    v += __shfl_xor(v, 8, 64);
    v += __shfl_xor(v, 4, 64);
    v += __shfl_xor(v, 2, 64);
    v += __shfl_xor(v, 1, 64);
    if (t == 0) out[0] = v * (1.0f / (float)BATCH);
}

extern "C" void kernel_launch(void* const* d_in, const int* in_sizes, int n_in,
                              void* d_out, int out_size, void* d_ws, size_t ws_size,
                              hipStream_t stream) {
    const int*   data = (const int*)d_in[0];     // (BATCH,5) int32
    const float* ent  = (const float*)d_in[1];   // (N_ENT,128) f32
    const float* rel  = (const float*)d_in[2];   // (N_REL,128,128) f32
    float* out = (float*)d_out;
    int*   wsi = (int*)d_ws;

    // zero counter + chunk table + accumulator slots (all below 64 KB)
    hipMemsetAsync(d_ws, 0, 65536, stream);
    k_bucket<<<N_REL, 256, 0, stream>>>(data, wsi);
    k_main<<<GRID_MAIN, 256, 0, stream>>>(ent, rel, wsi);
    k_final<<<1, 64, 0, stream>>>(wsi, out);
}